// Round 4
// baseline (2776.701 us; speedup 1.0000x reference)
//
#include <hip/hip_runtime.h>

typedef unsigned short u16;
typedef unsigned int u32;
typedef unsigned long long uptr;

typedef __bf16 bf16x8 __attribute__((ext_vector_type(8)));
typedef float f32x4 __attribute__((ext_vector_type(4)));
typedef u16 u16x8 __attribute__((ext_vector_type(8)));
typedef u16 u16x4 __attribute__((ext_vector_type(4)));
typedef u16 u16x2 __attribute__((ext_vector_type(2)));

static __device__ __forceinline__ u16 f2bf(float f) {
    u32 x = __float_as_uint(f);
    u32 r = x + 0x7fffu + ((x >> 16) & 1u);
    return (u16)(r >> 16);
}
static __device__ __forceinline__ float bf2f(u16 u) {
    return __uint_as_float(((u32)u) << 16);
}

// async global->LDS, 16B per lane. lds arg must be the wave-uniform base;
// HW scatters lane i's 16B to base + i*16. Global address is per-lane.
static __device__ __forceinline__ void async_cp16(const u16* g, const u16* lds) {
    __builtin_amdgcn_global_load_lds(
        (__attribute__((address_space(1))) u32*)(uptr)(const void*)g,
        (__attribute__((address_space(3))) u32*)(u32)(uptr)(const void*)lds,
        16, 0, 0);
}

enum { E_F32 = 0, E_BF16 = 1, E_BIASRES = 2, E_LEAKY = 3, E_RES = 4, E_VT = 5, E_EXPT = 6 };

// TN GEMM: A [M,K] row-major bf16, B [N,K] row-major bf16 (i.e. B^T storage).
// 128x128 tile, 4 waves (2x2 of 64x64), mfma_f32_16x16x32_bf16, BK=32,
// global_load_lds staging, 2-barrier K loop (m97 structure).
template <int EPI>
__global__ __launch_bounds__(256, 2) void gemm_tn(
    const u16* __restrict__ A, const u16* __restrict__ B, void* __restrict__ C,
    const float* __restrict__ bias, const float* __restrict__ res,
    float* __restrict__ colsum,
    int K, int lda, int ldb, int ldc, int H, int ZS,
    long sAb, long sAh, long sBb, long sBh, long sCb, long sCh, long sCz)
{
    constexpr bool TRANSOUT = (EPI == E_VT || EPI == E_EXPT);
    __shared__ u16 smem[TRANSOUT ? 17408 : 8192];  // stage: As [0,4096) Bs [4096,8192) u16s

    const int tid  = threadIdx.x;
    const int lane = tid & 63;
    const int wid  = tid >> 6;
    const int wm   = (wid >> 1) * 64;
    const int wn   = (wid & 1) * 64;
    const int m0   = blockIdx.y * 128;
    const int n0   = blockIdx.x * 128;
    const int z    = blockIdx.z;
    const int bb   = z / (H * ZS);
    const int hh   = (z / ZS) % H;
    const int zsp  = z % ZS;

    const u16* Ab = A + bb * sAb + hh * sAh + (long)zsp * K;
    const u16* Bb = B + bb * sBb + hh * sBh + (long)zsp * K;

    // staging: per wave, 2 chunks of 1KB per operand; LDS dest uniform base + lane*16
    const int srow = wid * 32 + (lane >> 2);
    const int skel = (lane & 3) * 8;
    const u16* aS = Ab + (long)(m0 + srow) * lda + skel;
    const u16* bS = Bb + (long)(n0 + srow) * ldb + skel;

    const int aoff = (wm + (lane & 15)) * 32 + (lane >> 4) * 8;         // u16 units
    const int boff = 4096 + (wn + (lane & 15)) * 32 + (lane >> 4) * 8;  // u16 units

    f32x4 acc[4][4] = {};

    const int nk = K >> 5;
    for (int kt = 0; kt < nk; ++kt) {
        __syncthreads();
        const u16* a0 = aS + kt * 32;
        const u16* b0 = bS + kt * 32;
        async_cp16(a0,            smem + wid * 1024);
        async_cp16(a0 + 16 * lda, smem + wid * 1024 + 512);
        async_cp16(b0,            smem + 4096 + wid * 1024);
        async_cp16(b0 + 16 * ldb, smem + 4096 + wid * 1024 + 512);
        __syncthreads();

        bf16x8 af[4], bfg[4];
#pragma unroll
        for (int i = 0; i < 4; ++i) af[i]  = *(const bf16x8*)(smem + aoff + i * 512);
#pragma unroll
        for (int i = 0; i < 4; ++i) bfg[i] = *(const bf16x8*)(smem + boff + i * 512);
#pragma unroll
        for (int mi = 0; mi < 4; ++mi)
#pragma unroll
            for (int ni = 0; ni < 4; ++ni)
                acc[mi][ni] = __builtin_amdgcn_mfma_f32_16x16x32_bf16(af[mi], bfg[ni], acc[mi][ni], 0, 0, 0);
    }

    const int r0 = (lane >> 4) * 4;
    const int cc = lane & 15;

    if constexpr (EPI == E_F32 || EPI == E_BIASRES || EPI == E_RES) {
        float* Cf = (float*)C + bb * sCb + hh * sCh + (long)zsp * sCz;
#pragma unroll
        for (int mi = 0; mi < 4; ++mi)
#pragma unroll
            for (int ni = 0; ni < 4; ++ni) {
                const int col = n0 + wn + ni * 16 + cc;
#pragma unroll
                for (int r = 0; r < 4; ++r) {
                    const int row = m0 + wm + mi * 16 + r0 + r;
                    float v = acc[mi][ni][r];
                    if constexpr (EPI == E_BIASRES) v += bias[col] + res[(long)row * ldc + col];
                    if constexpr (EPI == E_RES)     v += res[(long)row * ldc + col];
                    Cf[(long)row * ldc + col] = v;
                }
            }
    } else if constexpr (EPI == E_BF16 || EPI == E_LEAKY) {
        u16* Cb = (u16*)C + bb * sCb + hh * sCh;
#pragma unroll
        for (int mi = 0; mi < 4; ++mi)
#pragma unroll
            for (int ni = 0; ni < 4; ++ni) {
                const int col = n0 + wn + ni * 16 + cc;
#pragma unroll
                for (int r = 0; r < 4; ++r) {
                    const int row = m0 + wm + mi * 16 + r0 + r;
                    float v = acc[mi][ni][r];
                    if constexpr (EPI == E_LEAKY) v = (v >= 0.f) ? v : 0.01f * v;
                    Cb[(long)row * ldc + col] = f2bf(v);
                }
            }
    } else {
        // TRANSOUT: write C^T as bf16 into out[(batch*1024 + col)*4096 + row_in_batch]
        __syncthreads();
#pragma unroll
        for (int mi = 0; mi < 4; ++mi)
#pragma unroll
            for (int ni = 0; ni < 4; ++ni)
#pragma unroll
                for (int r = 0; r < 4; ++r) {
                    float v = acc[mi][ni][r];
                    if constexpr (EPI == E_EXPT) v = __expf(v);
                    smem[(wn + ni * 16 + cc) * 136 + wm + mi * 16 + r0 + r] = f2bf(v);
                }
        __syncthreads();
        const int c = tid >> 1, hf = tid & 1;
        const u16* srcp = smem + c * 136 + hf * 64;
        const long base = ((long)(m0 >> 12) * 1024 + n0 + c) * 4096 + (m0 & 4095) + hf * 64;
        u16* Ob = (u16*)C;
        float s = 0.f;
#pragma unroll
        for (int j = 0; j < 8; ++j) {
            u16x8 vv = *(const u16x8*)(srcp + j * 8);
            if constexpr (EPI == E_EXPT) {
#pragma unroll
                for (int q = 0; q < 8; ++q) s += bf2f(vv[q]);
            }
            *(u16x8*)(Ob + base + j * 8) = vv;
        }
        if constexpr (EPI == E_EXPT) {
            s += __shfl_xor(s, 1);
            if (hf == 0) atomicAdd(&colsum[(m0 >> 12) * 1024 + n0 + c], s);
        }
    }
}

// LayerNorm: fp32 in -> bf16 out. One row (1024) per block of 256.
__global__ __launch_bounds__(256) void layernorm_k(
    const float* __restrict__ x, const float* __restrict__ w,
    const float* __restrict__ b, u16* __restrict__ out)
{
    const int row = blockIdx.x, tid = threadIdx.x, lane = tid & 63, wid = tid >> 6;
    float4 v = ((const float4*)x)[row * 256 + tid];
    float s  = v.x + v.y + v.z + v.w;
    float ss = v.x * v.x + v.y * v.y + v.z * v.z + v.w * v.w;
#pragma unroll
    for (int o = 32; o >= 1; o >>= 1) { s += __shfl_xor(s, o); ss += __shfl_xor(ss, o); }
    __shared__ float red[8];
    if (lane == 0) { red[wid] = s; red[4 + wid] = ss; }
    __syncthreads();
    s  = red[0] + red[1] + red[2] + red[3];
    ss = red[4] + red[5] + red[6] + red[7];
    const float mean = s * (1.f / 1024.f);
    const float var  = ss * (1.f / 1024.f) - mean * mean;
    const float rs   = rsqrtf(var + 1e-5f);
    float4 wv = ((const float4*)w)[tid];
    float4 bv = ((const float4*)b)[tid];
    u16x4 o;
    o[0] = f2bf((v.x - mean) * rs * wv.x + bv.x);
    o[1] = f2bf((v.y - mean) * rs * wv.y + bv.y);
    o[2] = f2bf((v.z - mean) * rs * wv.z + bv.z);
    o[3] = f2bf((v.w - mean) * rs * wv.w + bv.w);
    *(u16x4*)(out + (long)row * 1024 + tid * 4) = o;
}

// In-place softmax over 128-wide head segments of q (bf16). 1 wave per segment.
__global__ __launch_bounds__(256) void qsoftmax_k(u16* __restrict__ q)
{
    const int tid = threadIdx.x, lane = tid & 63, wid = tid >> 6;
    const long seg = (long)blockIdx.x * 4 + wid;
    u16* p = q + seg * 128;
    u16x2 raw = *(const u16x2*)(p + lane * 2);
    float a = bf2f(raw[0]), b = bf2f(raw[1]);
    float m = fmaxf(a, b);
#pragma unroll
    for (int o = 32; o >= 1; o >>= 1) m = fmaxf(m, __shfl_xor(m, o));
    float e0 = __expf(a - m), e1 = __expf(b - m);
    float s = e0 + e1;
#pragma unroll
    for (int o = 32; o >= 1; o >>= 1) s += __shfl_xor(s, o);
    const float inv = 1.f / s;
    u16x2 o2; o2[0] = f2bf(e0 * inv); o2[1] = f2bf(e1 * inv);
    *(u16x2*)(p + lane * 2) = o2;
}

// Reduce context K-split partials, apply 1/colsum(d), write bf16 ctx_t[bh][e][d].
__global__ __launch_bounds__(256) void ctxreduce_k(
    const float* __restrict__ part, const float* __restrict__ S, u16* __restrict__ ctxb)
{
    const int idx = blockIdx.x * 256 + threadIdx.x;  // 0..262143
    const int bh = idx >> 14;
    const int d  = idx & 127;
    float s = 0.f;
#pragma unroll
    for (int ks = 0; ks < 16; ++ks) s += part[(long)(bh * 16 + ks) * 16384 + (idx & 16383)];
    s /= S[(bh >> 3) * 1024 + (bh & 7) * 128 + d];
    ctxb[idx] = f2bf(s);
}

// Transpose fp32 [R,C] -> bf16 [C,R], 64x64 tiles via LDS. grid.z = matrix index.
__global__ __launch_bounds__(256) void transw_k(
    const float* __restrict__ in, u16* __restrict__ out, int R, int C)
{
    __shared__ u16 t[64 * 68];
    const long moff = (long)blockIdx.z * R * C;
    const float* inp = in + moff;
    u16* outp = out + moff;
    const int r0 = blockIdx.y * 64, c0 = blockIdx.x * 64;
    const int tid = threadIdx.x;
    const int rr = tid >> 4, c4 = (tid & 15) * 4;
#pragma unroll
    for (int i = 0; i < 4; ++i) {
        const int r = rr + i * 16;
        float4 v = *(const float4*)(inp + (long)(r0 + r) * C + c0 + c4);
        u16x4 h; h[0] = f2bf(v.x); h[1] = f2bf(v.y); h[2] = f2bf(v.z); h[3] = f2bf(v.w);
        *(u16x4*)(t + r * 68 + c4) = h;
    }
    __syncthreads();
    const int c = tid >> 2, rs = (tid & 3) * 16;
    u16x8 o0, o1;
#pragma unroll
    for (int i = 0; i < 8; ++i) o0[i] = t[(rs + i) * 68 + c];
#pragma unroll
    for (int i = 0; i < 8; ++i) o1[i] = t[(rs + 8 + i) * 68 + c];
    u16* dst = outp + (long)(c0 + c) * R + r0 + rs;
    *(u16x8*)dst = o0;
    *(u16x8*)(dst + 8) = o1;
}

extern "C" void kernel_launch(void* const* d_in, const int* in_sizes, int n_in,
                              void* d_out, int out_size, void* d_ws, size_t ws_size,
                              hipStream_t stream)
{
    const float* x0   = (const float*)d_in[0];
    const float* ln1w = (const float*)d_in[1];
    const float* ln1b = (const float*)d_in[2];
    const float* wq   = (const float*)d_in[3];
    const float* wk   = (const float*)d_in[4];
    const float* wv   = (const float*)d_in[5];
    const float* wo   = (const float*)d_in[6];
    const float* bo   = (const float*)d_in[7];
    const float* ln2w = (const float*)d_in[8];
    const float* ln2b = (const float*)d_in[9];
    const float* w1   = (const float*)d_in[10];
    const float* w2   = (const float*)d_in[11];
    float* xout = (float*)d_out;

    char* ws = (char*)d_ws;
    size_t off = 0;
    auto alloc = [&](size_t bytes) -> void* {
        void* p = ws + off;
        off += (bytes + 255) & ~(size_t)255;
        return p;
    };
    u16* wqt   = (u16*)alloc(6ull * 1024 * 1024 * 2);
    u16* wkt   = (u16*)alloc(6ull * 1024 * 1024 * 2);
    u16* wvt   = (u16*)alloc(6ull * 1024 * 1024 * 2);
    u16* wot   = (u16*)alloc(6ull * 1024 * 1024 * 2);
    u16* w1t   = (u16*)alloc(6ull * 1024 * 4096 * 2);
    u16* w2t   = (u16*)alloc(6ull * 4096 * 1024 * 2);
    u16* xn    = (u16*)alloc(8192ull * 1024 * 2);
    u16* qb    = (u16*)alloc(8192ull * 1024 * 2);
    u16* kt    = (u16*)alloc(8192ull * 1024 * 2);
    u16* vt    = (u16*)alloc(8192ull * 1024 * 2);
    u16* attnb = (u16*)alloc(8192ull * 1024 * 2);
    u16* hdn   = (u16*)alloc(8192ull * 4096 * 2);
    float* part = (float*)alloc(256ull * 16384 * 4);
    u16* ctxb  = (u16*)alloc(262144ull * 2);
    float* Ssum = (float*)alloc(8192);

    const dim3 blk(256);

    transw_k<<<dim3(16, 16, 6), blk, 0, stream>>>(wq, wqt, 1024, 1024);
    transw_k<<<dim3(16, 16, 6), blk, 0, stream>>>(wk, wkt, 1024, 1024);
    transw_k<<<dim3(16, 16, 6), blk, 0, stream>>>(wv, wvt, 1024, 1024);
    transw_k<<<dim3(16, 16, 6), blk, 0, stream>>>(wo, wot, 1024, 1024);
    transw_k<<<dim3(64, 16, 6), blk, 0, stream>>>(w1, w1t, 1024, 4096);
    transw_k<<<dim3(16, 64, 6), blk, 0, stream>>>(w2, w2t, 4096, 1024);

    for (int L = 0; L < 6; ++L) {
        const float* xin = (L == 0) ? x0 : xout;

        layernorm_k<<<8192, blk, 0, stream>>>(xin, ln1w + L * 1024, ln1b + L * 1024, xn);

        // Q = xn @ wq  -> bf16
        gemm_tn<E_BF16><<<dim3(8, 64, 1), blk, 0, stream>>>(
            xn, wqt + (size_t)L * 1048576, qb, nullptr, nullptr, nullptr,
            1024, 1024, 1024, 1024, 1, 1, 0, 0, 0, 0, 0, 0, 0);

        hipMemsetAsync(Ssum, 0, 8192, stream);

        // exp(K)^T -> kt [b][col][seq] + column sums
        gemm_tn<E_EXPT><<<dim3(8, 64, 1), blk, 0, stream>>>(
            xn, wkt + (size_t)L * 1048576, kt, nullptr, nullptr, Ssum,
            1024, 1024, 1024, 0, 1, 1, 0, 0, 0, 0, 0, 0, 0);

        // V^T -> vt [b][col][seq]
        gemm_tn<E_VT><<<dim3(8, 64, 1), blk, 0, stream>>>(
            xn, wvt + (size_t)L * 1048576, vt, nullptr, nullptr, nullptr,
            1024, 1024, 1024, 0, 1, 1, 0, 0, 0, 0, 0, 0, 0);

        qsoftmax_k<<<16384, blk, 0, stream>>>(qb);

        // ctx_t partials: [bh][e][d] += vt[e,:] . kt[d,:], K split 16x
        gemm_tn<E_F32><<<dim3(1, 1, 256), blk, 0, stream>>>(
            vt, kt, part, nullptr, nullptr, nullptr,
            256, 4096, 4096, 128, 8, 16,
            4194304L, 524288L, 4194304L, 524288L, 2097152L, 262144L, 16384L);

        ctxreduce_k<<<1024, blk, 0, stream>>>(part, Ssum, ctxb);

        // attn = q_sm @ ctx  -> bf16 [b,t,e]
        gemm_tn<E_BF16><<<dim3(1, 32, 16), blk, 0, stream>>>(
            qb, ctxb, attnb, nullptr, nullptr, nullptr,
            128, 1024, 128, 1024, 8, 1,
            4194304L, 128L, 131072L, 16384L, 4194304L, 128L, 0L);

        // x = attn @ wo + bo + x
        gemm_tn<E_BIASRES><<<dim3(8, 64, 1), blk, 0, stream>>>(
            attnb, wot + (size_t)L * 1048576, xout, bo + L * 1024, xin, nullptr,
            1024, 1024, 1024, 1024, 1, 1, 0, 0, 0, 0, 0, 0, 0);

        layernorm_k<<<8192, blk, 0, stream>>>(xout, ln2w + L * 1024, ln2b + L * 1024, xn);

        // hdn = leaky(xn @ w1) -> bf16
        gemm_tn<E_LEAKY><<<dim3(32, 64, 1), blk, 0, stream>>>(
            xn, w1t + (size_t)L * 4194304, hdn, nullptr, nullptr, nullptr,
            1024, 1024, 1024, 4096, 1, 1, 0, 0, 0, 0, 0, 0, 0);

        // x = hdn @ w2 + x
        gemm_tn<E_RES><<<dim3(8, 64, 1), blk, 0, stream>>>(
            hdn, w2t + (size_t)L * 4194304, xout, nullptr, xout, nullptr,
            4096, 4096, 4096, 1024, 1, 1, 0, 0, 0, 0, 0, 0, 0);
    }
}

// Round 5
// 2482.389 us; speedup vs baseline: 1.1186x; 1.1186x over previous
//
#include <hip/hip_runtime.h>

typedef unsigned short u16;
typedef unsigned int u32;
typedef unsigned long long uptr;

typedef __bf16 bf16x8 __attribute__((ext_vector_type(8)));
typedef float f32x4 __attribute__((ext_vector_type(4)));
typedef u16 u16x8 __attribute__((ext_vector_type(8)));
typedef u16 u16x4 __attribute__((ext_vector_type(4)));
typedef u16 u16x2 __attribute__((ext_vector_type(2)));

static __device__ __forceinline__ u16 f2bf(float f) {
    u32 x = __float_as_uint(f);
    u32 r = x + 0x7fffu + ((x >> 16) & 1u);
    return (u16)(r >> 16);
}
static __device__ __forceinline__ float bf2f(u16 u) {
    return __uint_as_float(((u32)u) << 16);
}

// async global->LDS, 16B per lane. lds arg must be the wave-uniform base;
// HW scatters lane i's 16B to base + i*16. Global address is per-lane.
static __device__ __forceinline__ void async_cp16(const u16* g, const u16* lds) {
    __builtin_amdgcn_global_load_lds(
        (__attribute__((address_space(1))) u32*)(uptr)(const void*)g,
        (__attribute__((address_space(3))) u32*)(u32)(uptr)(const void*)lds,
        16, 0, 0);
}

enum { E_F32 = 0, E_BF16 = 1, E_BIASRES = 2, E_LEAKY = 3, E_RES = 4, E_QKV = 5 };

// TN GEMM: A [M,K] row-major bf16, B [N,K] row-major bf16 (i.e. B^T storage).
// 128x128 tile, 4 waves (2x2 of 64x64), mfma_f32_16x16x32_bf16, BK=32,
// global_load_lds staging, 2-barrier K loop (m97 structure).
// T1: XCD-chunked bijective blockIdx swizzle (contiguous y-bands per XCD).
template <int EPI>
__global__ __launch_bounds__(256, 2) void gemm_tn(
    const u16* __restrict__ A, const u16* __restrict__ B, void* __restrict__ C,
    void* __restrict__ C2, void* __restrict__ C3,
    const float* __restrict__ bias, const float* __restrict__ res,
    float* __restrict__ colsum,
    int K, int lda, int ldb, int ldc, int H, int ZS,
    long sAb, long sAh, long sBb, long sBh, long sCb, long sCh, long sCz)
{
    __shared__ u16 smem[EPI == E_QKV ? 17408 : 8192];  // stage: As [0,4096) Bs [4096,8192)

    const int tid  = threadIdx.x;
    const int lane = tid & 63;
    const int wid  = tid >> 6;
    const int wm   = (wid >> 1) * 64;
    const int wn   = (wid & 1) * 64;

    // XCD swizzle: default dispatch round-robins consecutive linear ids across
    // 8 XCDs; remap so each XCD owns a contiguous chunk (y-band) of the grid.
    const int gx = gridDim.x;
    int lin = blockIdx.x + gx * blockIdx.y;
    const int nwg = gx * gridDim.y;
    if ((nwg & 7) == 0) {
        const int q8 = nwg >> 3;
        lin = (lin & 7) * q8 + (lin >> 3);
    }
    const int n0 = (lin % gx) * 128;
    const int m0 = (lin / gx) * 128;

    const int z    = blockIdx.z;
    const int bb   = z / (H * ZS);
    const int hh   = (z / ZS) % H;
    const int zsp  = z % ZS;

    const u16* Ab = A + bb * sAb + hh * sAh + (long)zsp * K;
    const u16* Bb = B + bb * sBb + hh * sBh + (long)zsp * K;

    // staging: per wave, 2 chunks of 1KB per operand; LDS dest uniform base + lane*16
    const int srow = wid * 32 + (lane >> 2);
    const int skel = (lane & 3) * 8;
    const u16* aS = Ab + (long)(m0 + srow) * lda + skel;
    const u16* bS = Bb + (long)(n0 + srow) * ldb + skel;

    const int aoff = (wm + (lane & 15)) * 32 + (lane >> 4) * 8;         // u16 units
    const int boff = 4096 + (wn + (lane & 15)) * 32 + (lane >> 4) * 8;  // u16 units

    f32x4 acc[4][4] = {};

    const int nk = K >> 5;
    for (int kt = 0; kt < nk; ++kt) {
        __syncthreads();
        const u16* a0 = aS + kt * 32;
        const u16* b0 = bS + kt * 32;
        async_cp16(a0,            smem + wid * 1024);
        async_cp16(a0 + 16 * lda, smem + wid * 1024 + 512);
        async_cp16(b0,            smem + 4096 + wid * 1024);
        async_cp16(b0 + 16 * ldb, smem + 4096 + wid * 1024 + 512);
        __syncthreads();

        bf16x8 af[4], bfg[4];
#pragma unroll
        for (int i = 0; i < 4; ++i) af[i]  = *(const bf16x8*)(smem + aoff + i * 512);
#pragma unroll
        for (int i = 0; i < 4; ++i) bfg[i] = *(const bf16x8*)(smem + boff + i * 512);
#pragma unroll
        for (int mi = 0; mi < 4; ++mi)
#pragma unroll
            for (int ni = 0; ni < 4; ++ni)
                acc[mi][ni] = __builtin_amdgcn_mfma_f32_16x16x32_bf16(af[mi], bfg[ni], acc[mi][ni], 0, 0, 0);
    }

    const int r0 = (lane >> 4) * 4;
    const int cc = lane & 15;

    if constexpr (EPI == E_F32 || EPI == E_BIASRES || EPI == E_RES) {
        float* Cf = (float*)C + bb * sCb + hh * sCh + (long)zsp * sCz;
#pragma unroll
        for (int mi = 0; mi < 4; ++mi)
#pragma unroll
            for (int ni = 0; ni < 4; ++ni) {
                const int col = n0 + wn + ni * 16 + cc;
#pragma unroll
                for (int r = 0; r < 4; ++r) {
                    const int row = m0 + wm + mi * 16 + r0 + r;
                    float v = acc[mi][ni][r];
                    if constexpr (EPI == E_BIASRES) v += bias[col] + res[(long)row * ldc + col];
                    if constexpr (EPI == E_RES)     v += res[(long)row * ldc + col];
                    Cf[(long)row * ldc + col] = v;
                }
            }
    } else if constexpr (EPI == E_BF16 || EPI == E_LEAKY) {
        u16* Cb = (u16*)C + bb * sCb + hh * sCh;
#pragma unroll
        for (int mi = 0; mi < 4; ++mi)
#pragma unroll
            for (int ni = 0; ni < 4; ++ni) {
                const int col = n0 + wn + ni * 16 + cc;
#pragma unroll
                for (int r = 0; r < 4; ++r) {
                    const int row = m0 + wm + mi * 16 + r0 + r;
                    float v = acc[mi][ni][r];
                    if constexpr (EPI == E_LEAKY) v = (v >= 0.f) ? v : 0.01f * v;
                    Cb[(long)row * ldc + col] = f2bf(v);
                }
            }
    } else if constexpr (EPI == E_QKV) {
        // n0 in [0,1024): Q -> bf16 row-major (C). [1024,2048): exp(K)^T -> C2
        // (+colsum). [2048,3072): V^T -> C3. Transposed outs: [b][col][seq] bf16.
        if (n0 < 1024) {
            u16* Cb = (u16*)C;
#pragma unroll
            for (int mi = 0; mi < 4; ++mi)
#pragma unroll
                for (int ni = 0; ni < 4; ++ni) {
                    const int col = n0 + wn + ni * 16 + cc;
#pragma unroll
                    for (int r = 0; r < 4; ++r) {
                        const int row = m0 + wm + mi * 16 + r0 + r;
                        Cb[(long)row * ldc + col] = f2bf(acc[mi][ni][r]);
                    }
                }
        } else {
            const bool isK = (n0 < 2048);
            const int nb = n0 - (isK ? 1024 : 2048);
            __syncthreads();
#pragma unroll
            for (int mi = 0; mi < 4; ++mi)
#pragma unroll
                for (int ni = 0; ni < 4; ++ni)
#pragma unroll
                    for (int r = 0; r < 4; ++r) {
                        float v = acc[mi][ni][r];
                        if (isK) v = __expf(v);
                        smem[(wn + ni * 16 + cc) * 136 + wm + mi * 16 + r0 + r] = f2bf(v);
                    }
            __syncthreads();
            const int c = tid >> 1, hf = tid & 1;
            const u16* srcp = smem + c * 136 + hf * 64;
            const long base = ((long)(m0 >> 12) * 1024 + nb + c) * 4096 + (m0 & 4095) + hf * 64;
            u16* Ob = (u16*)(isK ? C2 : C3);
            float s = 0.f;
#pragma unroll
            for (int j = 0; j < 8; ++j) {
                u16x8 vv = *(const u16x8*)(srcp + j * 8);
                if (isK) {
#pragma unroll
                    for (int qq = 0; qq < 8; ++qq) s += bf2f(vv[qq]);
                }
                *(u16x8*)(Ob + base + j * 8) = vv;
            }
            if (isK) {
                s += __shfl_xor(s, 1);
                if (hf == 0) atomicAdd(&colsum[(m0 >> 12) * 1024 + nb + c], s);
            }
        }
    }
}

// LayerNorm: fp32 in -> bf16 out. One row (1024) per block of 256.
__global__ __launch_bounds__(256) void layernorm_k(
    const float* __restrict__ x, const float* __restrict__ w,
    const float* __restrict__ b, u16* __restrict__ out)
{
    const int row = blockIdx.x, tid = threadIdx.x, lane = tid & 63, wid = tid >> 6;
    float4 v = ((const float4*)x)[row * 256 + tid];
    float s  = v.x + v.y + v.z + v.w;
    float ss = v.x * v.x + v.y * v.y + v.z * v.z + v.w * v.w;
#pragma unroll
    for (int o = 32; o >= 1; o >>= 1) { s += __shfl_xor(s, o); ss += __shfl_xor(ss, o); }
    __shared__ float red[8];
    if (lane == 0) { red[wid] = s; red[4 + wid] = ss; }
    __syncthreads();
    s  = red[0] + red[1] + red[2] + red[3];
    ss = red[4] + red[5] + red[6] + red[7];
    const float mean = s * (1.f / 1024.f);
    const float var  = ss * (1.f / 1024.f) - mean * mean;
    const float rs   = rsqrtf(var + 1e-5f);
    float4 wv = ((const float4*)w)[tid];
    float4 bv = ((const float4*)b)[tid];
    u16x4 o;
    o[0] = f2bf((v.x - mean) * rs * wv.x + bv.x);
    o[1] = f2bf((v.y - mean) * rs * wv.y + bv.y);
    o[2] = f2bf((v.z - mean) * rs * wv.z + bv.z);
    o[3] = f2bf((v.w - mean) * rs * wv.w + bv.w);
    *(u16x4*)(out + (long)row * 1024 + tid * 4) = o;
}

// In-place softmax over 128-wide head segments of q (bf16). 1 wave per segment.
__global__ __launch_bounds__(256) void qsoftmax_k(u16* __restrict__ q)
{
    const int tid = threadIdx.x, lane = tid & 63, wid = tid >> 6;
    const long seg = (long)blockIdx.x * 4 + wid;
    u16* p = q + seg * 128;
    u16x2 raw = *(const u16x2*)(p + lane * 2);
    float a = bf2f(raw[0]), b = bf2f(raw[1]);
    float m = fmaxf(a, b);
#pragma unroll
    for (int o = 32; o >= 1; o >>= 1) m = fmaxf(m, __shfl_xor(m, o));
    float e0 = __expf(a - m), e1 = __expf(b - m);
    float s = e0 + e1;
#pragma unroll
    for (int o = 32; o >= 1; o >>= 1) s += __shfl_xor(s, o);
    const float inv = 1.f / s;
    u16x2 o2; o2[0] = f2bf(e0 * inv); o2[1] = f2bf(e1 * inv);
    *(u16x2*)(p + lane * 2) = o2;
}

// Reduce context K-split partials, apply 1/colsum(d), write bf16 ctx_t[bh][e][d].
__global__ __launch_bounds__(256) void ctxreduce_k(
    const float* __restrict__ part, const float* __restrict__ S, u16* __restrict__ ctxb)
{
    const int idx = blockIdx.x * 256 + threadIdx.x;  // 0..262143
    const int bh = idx >> 14;
    const int d  = idx & 127;
    float s = 0.f;
#pragma unroll
    for (int ks = 0; ks < 16; ++ks) s += part[(long)(bh * 16 + ks) * 16384 + (idx & 16383)];
    s /= S[(bh >> 3) * 1024 + (bh & 7) * 128 + d];
    ctxb[idx] = f2bf(s);
}

// Transpose fp32 [R,C] -> bf16 [C,R], 64x64 tiles via LDS. grid.z = matrix index
// (separate z-strides for in and out so outputs can pack into a fused buffer).
__global__ __launch_bounds__(256) void transw_k(
    const float* __restrict__ in, u16* __restrict__ out, int R, int C,
    long inZ, long outZ)
{
    __shared__ u16 t[64 * 68];
    const float* inp = in + (long)blockIdx.z * inZ;
    u16* outp = out + (long)blockIdx.z * outZ;
    const int r0 = blockIdx.y * 64, c0 = blockIdx.x * 64;
    const int tid = threadIdx.x;
    const int rr = tid >> 4, c4 = (tid & 15) * 4;
#pragma unroll
    for (int i = 0; i < 4; ++i) {
        const int r = rr + i * 16;
        float4 v = *(const float4*)(inp + (long)(r0 + r) * C + c0 + c4);
        u16x4 h; h[0] = f2bf(v.x); h[1] = f2bf(v.y); h[2] = f2bf(v.z); h[3] = f2bf(v.w);
        *(u16x4*)(t + r * 68 + c4) = h;
    }
    __syncthreads();
    const int c = tid >> 2, rs = (tid & 3) * 16;
    u16x8 o0, o1;
#pragma unroll
    for (int i = 0; i < 8; ++i) o0[i] = t[(rs + i) * 68 + c];
#pragma unroll
    for (int i = 0; i < 8; ++i) o1[i] = t[(rs + 8 + i) * 68 + c];
    u16* dst = outp + (long)(c0 + c) * R + r0 + rs;
    *(u16x8*)dst = o0;
    *(u16x8*)(dst + 8) = o1;
}

extern "C" void kernel_launch(void* const* d_in, const int* in_sizes, int n_in,
                              void* d_out, int out_size, void* d_ws, size_t ws_size,
                              hipStream_t stream)
{
    const float* x0   = (const float*)d_in[0];
    const float* ln1w = (const float*)d_in[1];
    const float* ln1b = (const float*)d_in[2];
    const float* wq   = (const float*)d_in[3];
    const float* wk   = (const float*)d_in[4];
    const float* wv   = (const float*)d_in[5];
    const float* wo   = (const float*)d_in[6];
    const float* bo   = (const float*)d_in[7];
    const float* ln2w = (const float*)d_in[8];
    const float* ln2b = (const float*)d_in[9];
    const float* w1   = (const float*)d_in[10];
    const float* w2   = (const float*)d_in[11];
    float* xout = (float*)d_out;

    char* ws = (char*)d_ws;
    size_t off = 0;
    auto alloc = [&](size_t bytes) -> void* {
        void* p = ws + off;
        off += (bytes + 255) & ~(size_t)255;
        return p;
    };
    u16* wqkvt = (u16*)alloc(6ull * 3072 * 1024 * 2);  // [L][3072][1024]: q|k|v
    u16* wot   = (u16*)alloc(6ull * 1024 * 1024 * 2);
    u16* w1t   = (u16*)alloc(6ull * 1024 * 4096 * 2);
    u16* w2t   = (u16*)alloc(6ull * 4096 * 1024 * 2);
    u16* xn    = (u16*)alloc(8192ull * 1024 * 2);
    u16* qb    = (u16*)alloc(8192ull * 1024 * 2);
    u16* kt    = (u16*)alloc(8192ull * 1024 * 2);
    u16* vt    = (u16*)alloc(8192ull * 1024 * 2);
    u16* attnb = (u16*)alloc(8192ull * 1024 * 2);
    u16* hdn   = (u16*)alloc(8192ull * 4096 * 2);
    float* part = (float*)alloc(256ull * 16384 * 4);
    u16* ctxb  = (u16*)alloc(262144ull * 2);
    float* Ssum = (float*)alloc(8192);

    const dim3 blk(256);

    transw_k<<<dim3(16, 16, 6), blk, 0, stream>>>(wq, wqkvt,           1024, 1024, 1048576L, 3145728L);
    transw_k<<<dim3(16, 16, 6), blk, 0, stream>>>(wk, wqkvt + 1048576, 1024, 1024, 1048576L, 3145728L);
    transw_k<<<dim3(16, 16, 6), blk, 0, stream>>>(wv, wqkvt + 2097152, 1024, 1024, 1048576L, 3145728L);
    transw_k<<<dim3(16, 16, 6), blk, 0, stream>>>(wo, wot, 1024, 1024, 1048576L, 1048576L);
    transw_k<<<dim3(64, 16, 6), blk, 0, stream>>>(w1, w1t, 1024, 4096, 4194304L, 4194304L);
    transw_k<<<dim3(16, 64, 6), blk, 0, stream>>>(w2, w2t, 4096, 1024, 4194304L, 4194304L);

    for (int L = 0; L < 6; ++L) {
        const float* xin = (L == 0) ? x0 : xout;

        layernorm_k<<<8192, blk, 0, stream>>>(xin, ln1w + L * 1024, ln1b + L * 1024, xn);

        hipMemsetAsync(Ssum, 0, 8192, stream);

        // Fused QKV: q->qb (bf16), exp(k)^T->kt (+colsum), v^T->vt
        gemm_tn<E_QKV><<<dim3(24, 64, 1), blk, 0, stream>>>(
            xn, wqkvt + (size_t)L * 3145728, qb, kt, vt, nullptr, nullptr, Ssum,
            1024, 1024, 1024, 1024, 1, 1, 0, 0, 0, 0, 0, 0, 0);

        qsoftmax_k<<<16384, blk, 0, stream>>>(qb);

        // ctx_t partials: [bh][e][d] += vt[e,:] . kt[d,:], K split 16x
        gemm_tn<E_F32><<<dim3(1, 1, 256), blk, 0, stream>>>(
            vt, kt, part, nullptr, nullptr, nullptr, nullptr, nullptr,
            256, 4096, 4096, 128, 8, 16,
            4194304L, 524288L, 4194304L, 524288L, 2097152L, 262144L, 16384L);

        ctxreduce_k<<<1024, blk, 0, stream>>>(part, Ssum, ctxb);

        // attn = q_sm @ ctx  -> bf16 [b,t,e]
        gemm_tn<E_BF16><<<dim3(1, 32, 16), blk, 0, stream>>>(
            qb, ctxb, attnb, nullptr, nullptr, nullptr, nullptr, nullptr,
            128, 1024, 128, 1024, 8, 1,
            4194304L, 128L, 131072L, 16384L, 4194304L, 128L, 0L);

        // x = attn @ wo + bo + x
        gemm_tn<E_BIASRES><<<dim3(8, 64, 1), blk, 0, stream>>>(
            attnb, wot + (size_t)L * 1048576, xout, nullptr, nullptr,
            bo + L * 1024, xin, nullptr,
            1024, 1024, 1024, 1024, 1, 1, 0, 0, 0, 0, 0, 0, 0);

        layernorm_k<<<8192, blk, 0, stream>>>(xout, ln2w + L * 1024, ln2b + L * 1024, xn);

        // hdn = leaky(xn @ w1) -> bf16
        gemm_tn<E_LEAKY><<<dim3(32, 64, 1), blk, 0, stream>>>(
            xn, w1t + (size_t)L * 4194304, hdn, nullptr, nullptr, nullptr, nullptr, nullptr,
            1024, 1024, 1024, 4096, 1, 1, 0, 0, 0, 0, 0, 0, 0);

        // x = hdn @ w2 + x
        gemm_tn<E_RES><<<dim3(8, 64, 1), blk, 0, stream>>>(
            hdn, w2t + (size_t)L * 4194304, xout, nullptr, nullptr,
            nullptr, xout, nullptr,
            4096, 4096, 4096, 1024, 1, 1, 0, 0, 0, 0, 0, 0, 0);
    }
}

// Round 7
// 2350.180 us; speedup vs baseline: 1.1815x; 1.0563x over previous
//
#include <hip/hip_runtime.h>

typedef unsigned short u16;
typedef unsigned int u32;
typedef unsigned long long uptr;

typedef __bf16 bf16x8 __attribute__((ext_vector_type(8)));
typedef float f32x4 __attribute__((ext_vector_type(4)));
typedef u16 u16x8 __attribute__((ext_vector_type(8)));
typedef u16 u16x4 __attribute__((ext_vector_type(4)));
typedef u16 u16x2 __attribute__((ext_vector_type(2)));

static __device__ __forceinline__ u16 f2bf(float f) {
    u32 x = __float_as_uint(f);
    u32 r = x + 0x7fffu + ((x >> 16) & 1u);
    return (u16)(r >> 16);
}
static __device__ __forceinline__ float bf2f(u16 u) {
    return __uint_as_float(((u32)u) << 16);
}

// async global->LDS, 16B per lane. lds arg must be the wave-uniform base;
// HW scatters lane i's 16B to base + i*16. Global address is per-lane.
static __device__ __forceinline__ void async_cp16(const u16* g, const u16* lds) {
    __builtin_amdgcn_global_load_lds(
        (__attribute__((address_space(1))) u32*)(uptr)(const void*)g,
        (__attribute__((address_space(3))) u32*)(u32)(uptr)(const void*)lds,
        16, 0, 0);
}

enum { E_F32 = 0, E_BF16 = 1, E_BIASRES = 2, E_LEAKY = 3, E_RES = 4, E_QKV = 5 };

// TN GEMM: A [M,K] row-major bf16, B [N,K] row-major bf16 (i.e. B^T storage).
// 128x128 tile, 4 waves (2x2 of 64x64), mfma_f32_16x16x32_bf16, BK=32.
// Double-buffered LDS: STAGE(t+1) issued before compute(t); ONE barrier/iter
// (its implicit vmcnt(0)+lgkmcnt(0) drain is covered by the MFMA phase).
// T1: XCD-chunked bijective blockIdx swizzle (contiguous y-bands per XCD).
template <int EPI>
__global__ __launch_bounds__(256, 4) void gemm_tn(
    const u16* __restrict__ A, const u16* __restrict__ B, void* __restrict__ C,
    void* __restrict__ C2, void* __restrict__ C3,
    const float* __restrict__ bias, const float* __restrict__ res,
    float* __restrict__ colsum,
    int K, int lda, int ldb, int ldc, int H, int ZS,
    long sAb, long sAh, long sBb, long sBh, long sCb, long sCh, long sCz)
{
    // dbuf staging: buf p at [p*8192, p*8192+8192) u16: A [0,4096) B [4096,8192)
    __shared__ u16 smem[EPI == E_QKV ? 17408 : 16384];

    const int tid  = threadIdx.x;
    const int lane = tid & 63;
    const int wid  = tid >> 6;
    const int wm   = (wid >> 1) * 64;
    const int wn   = (wid & 1) * 64;

    // XCD swizzle: default dispatch round-robins consecutive linear ids across
    // 8 XCDs; remap so each XCD owns a contiguous chunk (y-band) of the grid.
    const int gx = gridDim.x;
    int lin = blockIdx.x + gx * blockIdx.y;
    const int nwg = gx * gridDim.y;
    if ((nwg & 7) == 0) {
        const int q8 = nwg >> 3;
        lin = (lin & 7) * q8 + (lin >> 3);
    }
    const int n0 = (lin % gx) * 128;
    const int m0 = (lin / gx) * 128;

    const int z    = blockIdx.z;
    const int bb   = z / (H * ZS);
    const int hh   = (z / ZS) % H;
    const int zsp  = z % ZS;

    const u16* Ab = A + bb * sAb + hh * sAh + (long)zsp * K;
    const u16* Bb = B + bb * sBb + hh * sBh + (long)zsp * K;

    // staging: per wave, 2 chunks of 1KB per operand; LDS dest uniform base + lane*16
    const int srow = wid * 32 + (lane >> 2);
    const int skel = (lane & 3) * 8;
    const u16* aS = Ab + (long)(m0 + srow) * lda + skel;
    const u16* bS = Bb + (long)(n0 + srow) * ldb + skel;

    const int aoff = (wm + (lane & 15)) * 32 + (lane >> 4) * 8;         // u16 units
    const int boff = 4096 + (wn + (lane & 15)) * 32 + (lane >> 4) * 8;  // u16 units

    f32x4 acc[4][4] = {};

    const int nk = K >> 5;
    auto stage = [&](int t, int bsel) {
        const u16* a0 = aS + t * 32;
        const u16* b0 = bS + t * 32;
        u16* base = smem + bsel * 8192;
        async_cp16(a0,            base + wid * 1024);
        async_cp16(a0 + 16 * lda, base + wid * 1024 + 512);
        async_cp16(b0,            base + 4096 + wid * 1024);
        async_cp16(b0 + 16 * ldb, base + 4096 + wid * 1024 + 512);
    };

    stage(0, 0);
    for (int kt = 0; kt < nk; ++kt) {
        __syncthreads();   // drains vmcnt(0): buf[kt&1] ready; protects buf[(kt+1)&1] writes
        if (kt + 1 < nk) stage(kt + 1, (kt + 1) & 1);
        const u16* bufp = smem + (kt & 1) * 8192;

        bf16x8 af[4], bfg[4];
#pragma unroll
        for (int i = 0; i < 4; ++i) af[i]  = *(const bf16x8*)(bufp + aoff + i * 512);
#pragma unroll
        for (int i = 0; i < 4; ++i) bfg[i] = *(const bf16x8*)(bufp + boff + i * 512);
#pragma unroll
        for (int mi = 0; mi < 4; ++mi)
#pragma unroll
            for (int ni = 0; ni < 4; ++ni)
                acc[mi][ni] = __builtin_amdgcn_mfma_f32_16x16x32_bf16(af[mi], bfg[ni], acc[mi][ni], 0, 0, 0);
    }

    const int r0 = (lane >> 4) * 4;
    const int cc = lane & 15;

    if constexpr (EPI == E_F32 || EPI == E_BIASRES || EPI == E_RES) {
        float* Cf = (float*)C + bb * sCb + hh * sCh + (long)zsp * sCz;
#pragma unroll
        for (int mi = 0; mi < 4; ++mi)
#pragma unroll
            for (int ni = 0; ni < 4; ++ni) {
                const int col = n0 + wn + ni * 16 + cc;
#pragma unroll
                for (int r = 0; r < 4; ++r) {
                    const int row = m0 + wm + mi * 16 + r0 + r;
                    float v = acc[mi][ni][r];
                    if constexpr (EPI == E_BIASRES) v += bias[col] + res[(long)row * ldc + col];
                    if constexpr (EPI == E_RES)     v += res[(long)row * ldc + col];
                    Cf[(long)row * ldc + col] = v;
                }
            }
    } else if constexpr (EPI == E_BF16 || EPI == E_LEAKY) {
        u16* Cb = (u16*)C + bb * sCb + hh * sCh;
#pragma unroll
        for (int mi = 0; mi < 4; ++mi)
#pragma unroll
            for (int ni = 0; ni < 4; ++ni) {
                const int col = n0 + wn + ni * 16 + cc;
#pragma unroll
                for (int r = 0; r < 4; ++r) {
                    const int row = m0 + wm + mi * 16 + r0 + r;
                    float v = acc[mi][ni][r];
                    if constexpr (EPI == E_LEAKY) v = (v >= 0.f) ? v : 0.01f * v;
                    Cb[(long)row * ldc + col] = f2bf(v);
                }
            }
    } else if constexpr (EPI == E_QKV) {
        // n0 in [0,1024): Q -> bf16 row-major (C). [1024,2048): exp(K)^T -> C2
        // (+colsum). [2048,3072): V^T -> C3. Transposed outs: [b][col][seq] bf16.
        if (n0 < 1024) {
            u16* Cb = (u16*)C;
#pragma unroll
            for (int mi = 0; mi < 4; ++mi)
#pragma unroll
                for (int ni = 0; ni < 4; ++ni) {
                    const int col = n0 + wn + ni * 16 + cc;
#pragma unroll
                    for (int r = 0; r < 4; ++r) {
                        const int row = m0 + wm + mi * 16 + r0 + r;
                        Cb[(long)row * ldc + col] = f2bf(acc[mi][ni][r]);
                    }
                }
        } else {
            const bool isK = (n0 < 2048);
            const int nb = n0 - (isK ? 1024 : 2048);
            __syncthreads();
#pragma unroll
            for (int mi = 0; mi < 4; ++mi)
#pragma unroll
                for (int ni = 0; ni < 4; ++ni)
#pragma unroll
                    for (int r = 0; r < 4; ++r) {
                        float v = acc[mi][ni][r];
                        if (isK) v = __expf(v);
                        smem[(wn + ni * 16 + cc) * 136 + wm + mi * 16 + r0 + r] = f2bf(v);
                    }
            __syncthreads();
            const int c = tid >> 1, hf = tid & 1;
            const u16* srcp = smem + c * 136 + hf * 64;
            const long base = ((long)(m0 >> 12) * 1024 + nb + c) * 4096 + (m0 & 4095) + hf * 64;
            u16* Ob = (u16*)(isK ? C2 : C3);
            float s = 0.f;
#pragma unroll
            for (int j = 0; j < 8; ++j) {
                u16x8 vv = *(const u16x8*)(srcp + j * 8);
                if (isK) {
#pragma unroll
                    for (int qq = 0; qq < 8; ++qq) s += bf2f(vv[qq]);
                }
                *(u16x8*)(Ob + base + j * 8) = vv;
            }
            if (isK) {
                s += __shfl_xor(s, 1);
                if (hf == 0) atomicAdd(&colsum[(m0 >> 12) * 1024 + nb + c], s);
            }
        }
    }
}

// LayerNorm: fp32 in -> bf16 out. One row (1024) per block of 256.
__global__ __launch_bounds__(256) void layernorm_k(
    const float* __restrict__ x, const float* __restrict__ w,
    const float* __restrict__ b, u16* __restrict__ out)
{
    const int row = blockIdx.x, tid = threadIdx.x, lane = tid & 63, wid = tid >> 6;
    float4 v = ((const float4*)x)[row * 256 + tid];
    float s  = v.x + v.y + v.z + v.w;
    float ss = v.x * v.x + v.y * v.y + v.z * v.z + v.w * v.w;
#pragma unroll
    for (int o = 32; o >= 1; o >>= 1) { s += __shfl_xor(s, o); ss += __shfl_xor(ss, o); }
    __shared__ float red[8];
    if (lane == 0) { red[wid] = s; red[4 + wid] = ss; }
    __syncthreads();
    s  = red[0] + red[1] + red[2] + red[3];
    ss = red[4] + red[5] + red[6] + red[7];
    const float mean = s * (1.f / 1024.f);
    const float var  = ss * (1.f / 1024.f) - mean * mean;
    const float rs   = rsqrtf(var + 1e-5f);
    float4 wv = ((const float4*)w)[tid];
    float4 bv = ((const float4*)b)[tid];
    u16x4 o;
    o[0] = f2bf((v.x - mean) * rs * wv.x + bv.x);
    o[1] = f2bf((v.y - mean) * rs * wv.y + bv.y);
    o[2] = f2bf((v.z - mean) * rs * wv.z + bv.z);
    o[3] = f2bf((v.w - mean) * rs * wv.w + bv.w);
    *(u16x4*)(out + (long)row * 1024 + tid * 4) = o;
}

// In-place softmax over 128-wide head segments of q (bf16). 1 wave per segment.
__global__ __launch_bounds__(256) void qsoftmax_k(u16* __restrict__ q)
{
    const int tid = threadIdx.x, lane = tid & 63, wid = tid >> 6;
    const long seg = (long)blockIdx.x * 4 + wid;
    u16* p = q + seg * 128;
    u16x2 raw = *(const u16x2*)(p + lane * 2);
    float a = bf2f(raw[0]), b = bf2f(raw[1]);
    float m = fmaxf(a, b);
#pragma unroll
    for (int o = 32; o >= 1; o >>= 1) m = fmaxf(m, __shfl_xor(m, o));
    float e0 = __expf(a - m), e1 = __expf(b - m);
    float s = e0 + e1;
#pragma unroll
    for (int o = 32; o >= 1; o >>= 1) s += __shfl_xor(s, o);
    const float inv = 1.f / s;
    u16x2 o2; o2[0] = f2bf(e0 * inv); o2[1] = f2bf(e1 * inv);
    *(u16x2*)(p + lane * 2) = o2;
}

// Reduce context K-split partials, apply 1/colsum(d), write bf16 ctx_t[bh][e][d].
__global__ __launch_bounds__(256) void ctxreduce_k(
    const float* __restrict__ part, const float* __restrict__ S, u16* __restrict__ ctxb)
{
    const int idx = blockIdx.x * 256 + threadIdx.x;  // 0..262143
    const int bh = idx >> 14;
    const int d  = idx & 127;
    float s = 0.f;
#pragma unroll
    for (int ks = 0; ks < 16; ++ks) s += part[(long)(bh * 16 + ks) * 16384 + (idx & 16383)];
    s /= S[(bh >> 3) * 1024 + (bh & 7) * 128 + d];
    ctxb[idx] = f2bf(s);
}

// Transpose fp32 [R,C] -> bf16 [C,R], 64x64 tiles via LDS. grid.z = matrix index
// (separate z-strides for in and out so outputs can pack into a fused buffer).
__global__ __launch_bounds__(256) void transw_k(
    const float* __restrict__ in, u16* __restrict__ out, int R, int C,
    long inZ, long outZ)
{
    __shared__ u16 t[64 * 68];
    const float* inp = in + (long)blockIdx.z * inZ;
    u16* outp = out + (long)blockIdx.z * outZ;
    const int r0 = blockIdx.y * 64, c0 = blockIdx.x * 64;
    const int tid = threadIdx.x;
    const int rr = tid >> 4, c4 = (tid & 15) * 4;
#pragma unroll
    for (int i = 0; i < 4; ++i) {
        const int r = rr + i * 16;
        float4 v = *(const float4*)(inp + (long)(r0 + r) * C + c0 + c4);
        u16x4 h; h[0] = f2bf(v.x); h[1] = f2bf(v.y); h[2] = f2bf(v.z); h[3] = f2bf(v.w);
        *(u16x4*)(t + r * 68 + c4) = h;
    }
    __syncthreads();
    const int c = tid >> 2, rs = (tid & 3) * 16;
    u16x8 o0, o1;
#pragma unroll
    for (int i = 0; i < 8; ++i) o0[i] = t[(rs + i) * 68 + c];
#pragma unroll
    for (int i = 0; i < 8; ++i) o1[i] = t[(rs + 8 + i) * 68 + c];
    u16* dst = outp + (long)(c0 + c) * R + r0 + rs;
    *(u16x8*)dst = o0;
    *(u16x8*)(dst + 8) = o1;
}

extern "C" void kernel_launch(void* const* d_in, const int* in_sizes, int n_in,
                              void* d_out, int out_size, void* d_ws, size_t ws_size,
                              hipStream_t stream)
{
    const float* x0   = (const float*)d_in[0];
    const float* ln1w = (const float*)d_in[1];
    const float* ln1b = (const float*)d_in[2];
    const float* wq   = (const float*)d_in[3];
    const float* wk   = (const float*)d_in[4];
    const float* wv   = (const float*)d_in[5];
    const float* wo   = (const float*)d_in[6];
    const float* bo   = (const float*)d_in[7];
    const float* ln2w = (const float*)d_in[8];
    const float* ln2b = (const float*)d_in[9];
    const float* w1   = (const float*)d_in[10];
    const float* w2   = (const float*)d_in[11];
    float* xout = (float*)d_out;

    char* ws = (char*)d_ws;
    size_t off = 0;
    auto alloc = [&](size_t bytes) -> void* {
        void* p = ws + off;
        off += (bytes + 255) & ~(size_t)255;
        return p;
    };
    u16* wqkvt = (u16*)alloc(6ull * 3072 * 1024 * 2);  // [L][3072][1024]: q|k|v
    u16* wot   = (u16*)alloc(6ull * 1024 * 1024 * 2);
    u16* w1t   = (u16*)alloc(6ull * 1024 * 4096 * 2);
    u16* w2t   = (u16*)alloc(6ull * 4096 * 1024 * 2);
    u16* xn    = (u16*)alloc(8192ull * 1024 * 2);
    u16* qb    = (u16*)alloc(8192ull * 1024 * 2);
    u16* kt    = (u16*)alloc(8192ull * 1024 * 2);
    u16* vt    = (u16*)alloc(8192ull * 1024 * 2);
    u16* attnb = (u16*)alloc(8192ull * 1024 * 2);
    u16* hdn   = (u16*)alloc(8192ull * 4096 * 2);
    float* part = (float*)alloc(256ull * 16384 * 4);
    u16* ctxb  = (u16*)alloc(262144ull * 2);
    float* Ssum = (float*)alloc(8192);

    const dim3 blk(256);

    transw_k<<<dim3(16, 16, 6), blk, 0, stream>>>(wq, wqkvt,           1024, 1024, 1048576L, 3145728L);
    transw_k<<<dim3(16, 16, 6), blk, 0, stream>>>(wk, wqkvt + 1048576, 1024, 1024, 1048576L, 3145728L);
    transw_k<<<dim3(16, 16, 6), blk, 0, stream>>>(wv, wqkvt + 2097152, 1024, 1024, 1048576L, 3145728L);
    transw_k<<<dim3(16, 16, 6), blk, 0, stream>>>(wo, wot, 1024, 1024, 1048576L, 1048576L);
    transw_k<<<dim3(64, 16, 6), blk, 0, stream>>>(w1, w1t, 1024, 4096, 4194304L, 4194304L);
    transw_k<<<dim3(16, 64, 6), blk, 0, stream>>>(w2, w2t, 4096, 1024, 4194304L, 4194304L);

    for (int L = 0; L < 6; ++L) {
        const float* xin = (L == 0) ? x0 : xout;

        layernorm_k<<<8192, blk, 0, stream>>>(xin, ln1w + L * 1024, ln1b + L * 1024, xn);

        hipMemsetAsync(Ssum, 0, 8192, stream);

        // Fused QKV: q->qb (bf16), exp(k)^T->kt (+colsum), v^T->vt
        gemm_tn<E_QKV><<<dim3(24, 64, 1), blk, 0, stream>>>(
            xn, wqkvt + (size_t)L * 3145728, qb, kt, vt, nullptr, nullptr, Ssum,
            1024, 1024, 1024, 1024, 1, 1, 0, 0, 0, 0, 0, 0, 0);

        qsoftmax_k<<<16384, blk, 0, stream>>>(qb);

        // ctx_t partials: [bh][e][d] += vt[e,:] . kt[d,:], K split 16x
        gemm_tn<E_F32><<<dim3(1, 1, 256), blk, 0, stream>>>(
            vt, kt, part, nullptr, nullptr, nullptr, nullptr, nullptr,
            256, 4096, 4096, 128, 8, 16,
            4194304L, 524288L, 4194304L, 524288L, 2097152L, 262144L, 16384L);

        ctxreduce_k<<<1024, blk, 0, stream>>>(part, Ssum, ctxb);

        // attn = q_sm @ ctx  -> bf16 [b,t,e]
        gemm_tn<E_BF16><<<dim3(1, 32, 16), blk, 0, stream>>>(
            qb, ctxb, attnb, nullptr, nullptr, nullptr, nullptr, nullptr,
            128, 1024, 128, 1024, 8, 1,
            4194304L, 128L, 131072L, 16384L, 4194304L, 128L, 0L);

        // x = attn @ wo + bo + x
        gemm_tn<E_BIASRES><<<dim3(8, 64, 1), blk, 0, stream>>>(
            attnb, wot + (size_t)L * 1048576, xout, nullptr, nullptr,
            bo + L * 1024, xin, nullptr,
            1024, 1024, 1024, 1024, 1, 1, 0, 0, 0, 0, 0, 0, 0);

        layernorm_k<<<8192, blk, 0, stream>>>(xout, ln2w + L * 1024, ln2b + L * 1024, xn);

        // hdn = leaky(xn @ w1) -> bf16
        gemm_tn<E_LEAKY><<<dim3(32, 64, 1), blk, 0, stream>>>(
            xn, w1t + (size_t)L * 4194304, hdn, nullptr, nullptr, nullptr, nullptr, nullptr,
            1024, 1024, 1024, 4096, 1, 1, 0, 0, 0, 0, 0, 0, 0);

        // x = hdn @ w2 + x
        gemm_tn<E_RES><<<dim3(8, 64, 1), blk, 0, stream>>>(
            hdn, w2t + (size_t)L * 4194304, xout, nullptr, nullptr,
            nullptr, xout, nullptr,
            4096, 4096, 4096, 1024, 1, 1, 0, 0, 0, 0, 0, 0, 0);
    }
}